// Round 2
// baseline (4508.948 us; speedup 1.0000x reference)
//
#include <hip/hip_runtime.h>
#include <hip/hip_cooperative_groups.h>
#include <math.h>

namespace cg = cooperative_groups;
#define DEV __device__ __forceinline__

// ---------------- problem dims ----------------
// B=1024 V=50000 K=100 EU=200 E=200 G=20 P=384

// ---------------- ws layout (float offsets), total ~62.92M floats ~252MB ----
static constexpr long long OFF_X      = 0LL;                      // 51,200,000 (first 5,120,000 reused as gemm1 split-K partials)
static constexpr long long OFF_BETA   = 51200000LL;               // 5,000,000
static constexpr long long OFF_KM     = OFF_BETA  + 5000000LL;    // row-major [100][50000]
static constexpr long long OFF_E1     = OFF_KM    + 5000000LL;    // 204800
static constexpr long long OFF_E2     = OFF_E1    + 204800LL;
static constexpr long long OFF_MUPRE  = OFF_E2    + 204800LL;
static constexpr long long OFF_LVPRE  = OFF_MUPRE + 102400LL;
static constexpr long long OFF_BNM    = OFF_LVPRE + 102400LL;     // 200 used (mu 0..99, lv 100..199)
static constexpr long long OFF_BNR    = OFF_BNM   + 256LL;
static constexpr long long OFF_THETA  = OFF_BNR   + 256LL;
static constexpr long long OFF_THETAP = OFF_THETA + 102400LL;
static constexpr long long OFF_PBOW   = OFF_THETAP+ 393216LL;
static constexpr long long OFF_PBN    = OFF_PBOW  + 393216LL;
static constexpr long long OFF_BERTN  = OFF_PBN   + 1024LL;
static constexpr long long OFF_KM2    = OFF_BERTN + 1024LL;       // [1024][20]
static constexpr long long OFF_M2     = OFF_KM2   + 20480LL;
static constexpr long long OFF_TOPICP = OFF_M2    + 20480LL;      // [100][384]
static constexpr long long OFF_KM3    = OFF_TOPICP+ 38400LL;      // [100][20]
static constexpr long long OFF_M3     = OFF_KM3   + 2000LL;
static constexpr long long OFF_XMEAN  = OFF_M3    + 2000LL;       // 50000
static constexpr long long OFF_XRSTD  = OFF_XMEAN + 50000LL;
static constexpr long long OFF_TBUF   = OFF_XRSTD + 50000LL;      // [100][128] per-iteration u-exchange
static constexpr long long OFF_NCEP   = OFF_TBUF  + 12800LL;      // [1024][8][2] (m,s) LSE partials
static constexpr long long OFF_NCED   = OFF_NCEP  + 16384LL;      // diag cos
static constexpr long long OFF_ACC    = OFF_NCED  + 1024LL;       // 16 accumulators

DEV float softplusf(float x){ return fmaxf(x,0.f) + log1pf(expf(-fabsf(x))); }
DEV void  gAdd(float* p, float v){ unsafeAtomicAdd(p, v); }       // native f32 atomic (no CAS loop)
DEV float wsum(float v){ for(int d=1;d<64;d<<=1) v += __shfl_xor(v,d); return v; }
DEV float wmaxr(float v){ for(int d=1;d<64;d<<=1) v = fmaxf(v,__shfl_xor(v,d)); return v; }
DEV void  lse_merge(float& m, float& s, float mo, float so){
  float M = fmaxf(m, mo); s = s*expf(m-M) + so*expf(mo-M); m = M;
}

// ---------------- zero scratch accumulators ----------------
__global__ void k_zero(float* tbuf, float* accs){
  int t = blockIdx.x*256 + threadIdx.x;
  for (int i=t; i<12800; i+=13*256) tbuf[i] = 0.f;
  if (t < 16) accs[t] = 0.f;
}

// ---------------- GEMM1: e1_pre partials = data @ fc11_w (split-K) ----------------
// grid (16 mtiles, 25 ksplits), 256 thr. Block: [64 rows]x[200 cols], K-chunk 2000.
__global__ __launch_bounds__(256) void k_gemm1(const float* __restrict__ data,
                                               const float* __restrict__ w,
                                               float* __restrict__ part){
  __shared__ __align__(16) float a_lds[64*17];
  __shared__ __align__(16) float w_lds[16*208];   // 4 col-groups at padded stride 52
  int t = threadIdx.x, mt = blockIdx.x, ks = blockIdx.y;
  int rr = t & 63, g = t >> 6;
  int lr = t >> 2, lq = t & 3;
  float acc[50];
  #pragma unroll
  for (int c=0;c<50;c++) acc[c]=0.f;
  int row0 = mt*64;
  for (int k0 = ks*2000; k0 < ks*2000 + 2000; k0 += 16){
    float4 av = *(const float4*)(data + (long long)(row0+lr)*50000 + k0 + lq*4);
    a_lds[lr*17 + lq*4+0] = av.x; a_lds[lr*17 + lq*4+1] = av.y;
    a_lds[lr*17 + lq*4+2] = av.z; a_lds[lr*17 + lq*4+3] = av.w;
    for (int i=t; i<3200; i+=256){
      int kr = i/200, c = i - kr*200;
      w_lds[kr*208 + c + 2*(c/50)] = w[(k0+kr)*200 + c];
    }
    __syncthreads();
    #pragma unroll
    for (int kk=0; kk<16; kk++){
      float a = a_lds[rr*17 + kk];
      const float* wr = &w_lds[kk*208 + g*52];
      #pragma unroll
      for (int cc=0; cc<12; cc++){
        float4 w4 = *(const float4*)(wr + cc*4);
        acc[cc*4+0] += a*w4.x; acc[cc*4+1] += a*w4.y;
        acc[cc*4+2] += a*w4.z; acc[cc*4+3] += a*w4.w;
      }
      float2 w2 = *(const float2*)(wr + 48);
      acc[48] += a*w2.x; acc[49] += a*w2.y;
    }
    __syncthreads();
  }
  float* dst = part + (long long)ks*204800 + (row0+rr)*200 + g*50;
  #pragma unroll
  for (int cc=0; cc<25; cc++){
    float2 v; v.x = acc[2*cc]; v.y = acc[2*cc+1];
    *(float2*)(dst + cc*2) = v;
  }
}

// ---------------- reduce split-K partials + bias + softplus -> e1 ----------------
__global__ void k_e1red(const float* __restrict__ part, const float* __restrict__ b11,
                        float* __restrict__ e1){
  int idx = blockIdx.x*256 + threadIdx.x;   // grid 800 -> exactly 204800
  float s = 0.f;
  for (int ks=0; ks<25; ks++) s += part[(long long)ks*204800 + idx];
  s += b11[idx % 200];
  e1[idx] = softplusf(s);
}

// ---------------- e2 = softplus(e1 @ fc12_w + b) ----------------
__global__ __launch_bounds__(256) void k_e2(const float* __restrict__ e1,
                                            const float* __restrict__ w12,
                                            const float* __restrict__ b12,
                                            float* __restrict__ e2){
  __shared__ float wl[64*200];
  __shared__ __align__(16) float xl[64*16];   // transposed [k][16 rows]
  int t = threadIdx.x, r0 = blockIdx.x*16;
  int c = t; bool act = (c < 200);
  float acc[16];
  #pragma unroll
  for (int r=0;r<16;r++) acc[r]=0.f;
  for (int kc=0; kc<200; kc+=64){
    int kw = min(64, 200-kc);
    __syncthreads();
    for (int i=t; i<kw*200; i+=256){ int kr=i/200, cc=i-kr*200; wl[kr*200+cc] = w12[(kc+kr)*200+cc]; }
    for (int i=t; i<16*kw; i+=256){ int r=i/kw, k=i-r*kw; xl[k*16+r] = e1[(r0+r)*200 + kc + k]; }
    __syncthreads();
    if (act){
      for (int k=0;k<kw;k++){
        float wv = wl[k*200 + c];
        const float4 x0=*(const float4*)&xl[k*16+0], x1=*(const float4*)&xl[k*16+4];
        const float4 x2=*(const float4*)&xl[k*16+8], x3=*(const float4*)&xl[k*16+12];
        acc[0]+=x0.x*wv; acc[1]+=x0.y*wv; acc[2]+=x0.z*wv; acc[3]+=x0.w*wv;
        acc[4]+=x1.x*wv; acc[5]+=x1.y*wv; acc[6]+=x1.z*wv; acc[7]+=x1.w*wv;
        acc[8]+=x2.x*wv; acc[9]+=x2.y*wv; acc[10]+=x2.z*wv; acc[11]+=x2.w*wv;
        acc[12]+=x3.x*wv; acc[13]+=x3.y*wv; acc[14]+=x3.z*wv; acc[15]+=x3.w*wv;
      }
    }
  }
  if (act){
    float bb = b12[c];
    #pragma unroll
    for (int r=0;r<16;r++) e2[(r0+r)*200 + c] = softplusf(acc[r] + bb);
  }
}

// ---------------- mu_pre / lv_pre = e2 @ fc21_w / fc22_w + b ----------------
__global__ __launch_bounds__(256) void k_mulv(const float* __restrict__ e2,
                                              const float* __restrict__ w21, const float* __restrict__ b21,
                                              const float* __restrict__ w22, const float* __restrict__ b22,
                                              float* __restrict__ mupre, float* __restrict__ lvpre){
  __shared__ float w1[64*100], w2[64*100];
  __shared__ __align__(16) float xl[64*16];
  int t = threadIdx.x, r0 = blockIdx.x*16;
  bool act = (t < 200);
  int mat = t/100, c = t%100;
  float acc[16];
  #pragma unroll
  for (int r=0;r<16;r++) acc[r]=0.f;
  for (int kc=0; kc<200; kc+=64){
    int kw = min(64, 200-kc);
    __syncthreads();
    for (int i=t; i<kw*100; i+=256){ int kr=i/100, cc=i-kr*100;
      w1[kr*100+cc] = w21[(kc+kr)*100+cc]; w2[kr*100+cc] = w22[(kc+kr)*100+cc]; }
    for (int i=t; i<16*kw; i+=256){ int r=i/kw, k=i-r*kw; xl[k*16+r] = e2[(r0+r)*200 + kc + k]; }
    __syncthreads();
    if (act){
      const float* wm = mat ? w2 : w1;
      for (int k=0;k<kw;k++){
        float wv = wm[k*100 + c];
        const float4 x0=*(const float4*)&xl[k*16+0], x1=*(const float4*)&xl[k*16+4];
        const float4 x2=*(const float4*)&xl[k*16+8], x3=*(const float4*)&xl[k*16+12];
        acc[0]+=x0.x*wv; acc[1]+=x0.y*wv; acc[2]+=x0.z*wv; acc[3]+=x0.w*wv;
        acc[4]+=x1.x*wv; acc[5]+=x1.y*wv; acc[6]+=x1.z*wv; acc[7]+=x1.w*wv;
        acc[8]+=x2.x*wv; acc[9]+=x2.y*wv; acc[10]+=x2.z*wv; acc[11]+=x2.w*wv;
        acc[12]+=x3.x*wv; acc[13]+=x3.y*wv; acc[14]+=x3.z*wv; acc[15]+=x3.w*wv;
      }
    }
  }
  if (act){
    float bb = mat ? b22[c] : b21[c];
    float* out = mat ? lvpre : mupre;
    #pragma unroll
    for (int r=0;r<16;r++) out[(r0+r)*100 + c] = acc[r] + bb;
  }
}

// ---------------- batch-norm stats for mu_pre / lv_pre ----------------
__global__ void k_bnstats(const float* __restrict__ mupre, const float* __restrict__ lvpre,
                          float* __restrict__ bnm, float* __restrict__ bnr){
  __shared__ float ss[4][64], sq[4][64];
  int t = threadIdx.x, lane = t&63, rg = t>>6;
  int b = blockIdx.x;            // 0..3
  int arr = b>>1, c = (b&1)*64 + lane;
  const float* src = arr ? lvpre : mupre;
  float s=0.f, q=0.f;
  if (c < 100) for (int i=0;i<256;i++){ float v = src[(rg*256+i)*100 + c]; s+=v; q+=v*v; }
  ss[rg][lane]=s; sq[rg][lane]=q;
  __syncthreads();
  if (rg==0 && c<100){
    s = ss[0][lane]+ss[1][lane]+ss[2][lane]+ss[3][lane];
    q = sq[0][lane]+sq[1][lane]+sq[2][lane]+sq[3][lane];
    float mean = s*(1.f/1024.f);
    float var  = q*(1.f/1024.f) - mean*mean;
    bnm[arr*100+c] = mean;
    bnr[arr*100+c] = rsqrtf(var + 1e-5f);
  }
}

// ---------------- theta = softmax(z), KL accumulation ----------------
__global__ void k_theta(const float* __restrict__ mupre, const float* __restrict__ lvpre,
                        const float* __restrict__ bnm, const float* __restrict__ bnr,
                        const float* __restrict__ mbb, const float* __restrict__ lbb,
                        const float* __restrict__ eps, float* __restrict__ theta,
                        float* __restrict__ accs){
  int t = threadIdx.x, w = t>>6, l = t&63;
  int r = blockIdx.x*4 + w;       // grid 256 -> 1024 rows
  int k1 = l, k2 = 64+l; bool h2 = (l < 36);
  float mu1 = (mupre[r*100+k1]-bnm[k1])*bnr[k1] + mbb[k1];
  float lv1 = (lvpre[r*100+k1]-bnm[100+k1])*bnr[100+k1] + lbb[k1];
  float z1 = mu1 + eps[r*100+k1]*expf(0.5f*lv1);
  float mu2=0.f, lv2=0.f, z2=-INFINITY;
  if (h2){
    mu2 = (mupre[r*100+k2]-bnm[k2])*bnr[k2] + mbb[k2];
    lv2 = (lvpre[r*100+k2]-bnm[100+k2])*bnr[100+k2] + lbb[k2];
    z2 = mu2 + eps[r*100+k2]*expf(0.5f*lv2);
  }
  float m = wmaxr(fmaxf(z1, z2));
  float p1 = expf(z1-m), p2 = h2 ? expf(z2-m) : 0.f;
  float s = wsum(p1+p2);
  theta[r*100+k1] = p1/s;
  if (h2) theta[r*100+k2] = p2/s;
  const float iv2 = 1.0101010101010102f;        // 1/0.99
  const float lv2c = -0.010050335853501441f;    // ln(0.99)
  float kt = expf(lv1)*iv2 + mu1*mu1*iv2 + (lv2c - lv1);
  if (h2) kt += expf(lv2)*iv2 + mu2*mu2*iv2 + (lv2c - lv2);
  kt = wsum(kt);
  if (l==0) gAdd(accs+1, 0.5f*(kt - 100.f));
}

// ---------------- topic-word distances -> beta, Km ----------------
__global__ __launch_bounds__(256) void k_topicword(const float* __restrict__ topic,
                                                   const float* __restrict__ word,
                                                   float* __restrict__ beta,
                                                   float* __restrict__ km){
  __shared__ __align__(16) float tl[100*100];   // [e][k] transposed
  __shared__ float tn2[100];
  int t = threadIdx.x;
  int j = blockIdx.x*256 + t; bool act = j < 50000;
  float acc[100];
  #pragma unroll
  for (int k=0;k<100;k++) acc[k]=0.f;
  float wn = 0.f;
  if (t < 100) tn2[t] = 0.f;
  for (int ec=0; ec<200; ec+=100){
    __syncthreads();
    for (int i=t; i<10000; i+=256){ int kt_=i/100, e=i-kt_*100; tl[e*100+kt_] = topic[kt_*200 + ec + e]; }
    __syncthreads();
    if (t < 100){ float s=0.f; for (int e=0;e<100;e++){ float v=tl[e*100+t]; s+=v*v; } tn2[t]+=s; }
    if (act){
      for (int e=0;e<100;e++){
        float wv = word[(long long)j*200 + ec + e];
        wn += wv*wv;
        #pragma unroll
        for (int k4=0;k4<25;k4++){
          float4 tv = *(const float4*)&tl[e*100 + k4*4];
          acc[k4*4+0]+=tv.x*wv; acc[k4*4+1]+=tv.y*wv; acc[k4*4+2]+=tv.z*wv; acc[k4*4+3]+=tv.w*wv;
        }
      }
    }
  }
  __syncthreads();
  if (act){
    float dmin = INFINITY;
    #pragma unroll
    for (int k=0;k<100;k++){ float d = tn2[k] + wn - 2.f*acc[k]; acc[k]=d; dmin = fminf(dmin,d); }
    float ssum = 0.f;
    #pragma unroll
    for (int k=0;k<100;k++) ssum += expf(-5.f*(acc[k]-dmin));
    float rinv = 1.f/ssum;
    #pragma unroll
    for (int k=0;k<100;k++){
      float d = acc[k];
      beta[(long long)k*50000 + j] = expf(-5.f*(d-dmin))*rinv;
      km  [(long long)k*50000 + j] = expf(-20.f*d);
    }
  }
}

// ---------------- theta_p & pbow projections ----------------
__global__ void k_proj(const float* __restrict__ theta,
                       const float* __restrict__ thw, const float* __restrict__ thb,
                       const float* __restrict__ prw, const float* __restrict__ prb,
                       float* __restrict__ thetap, float* __restrict__ pbow){
  int gid = blockIdx.x*256 + threadIdx.x;     // grid 3072 -> 786432 exact
  int half = gid / 393216, idx = gid % 393216;
  int r = idx / 384, c = idx % 384;
  const float* W = half ? prw : thw;
  float s = 0.f;
  for (int k=0;k<100;k++) s += theta[r*100+k] * W[k*384+c];
  s += (half ? prb : thb)[c];
  (half ? pbow : thetap)[idx] = s;
}

// ---------------- row norms of pbow and bert ----------------
__global__ void k_norms(const float* __restrict__ pbow, const float* __restrict__ bert,
                        float* __restrict__ pbn, float* __restrict__ bertn){
  int t = threadIdx.x, w = t>>6, l = t&63;
  int task = blockIdx.x*4 + w;                // grid 512 -> 2048 exact
  int arr = task >> 10, r = task & 1023;
  const float* src = arr ? bert : pbow;
  float s = 0.f;
  #pragma unroll
  for (int q=0;q<6;q++){ float v = src[(long long)r*384 + q*64 + l]; s += v*v; }
  s = wsum(s);
  if (l==0) (arr ? bertn : pbn)[r] = sqrtf(s);
}

// ---------------- DCR distances: M2, Km2 ----------------
__global__ __launch_bounds__(256) void k_km2(const float* __restrict__ thetap,
                                             const float* __restrict__ cluster,
                                             float* __restrict__ m2, float* __restrict__ km2){
  __shared__ float tp[64*129];
  __shared__ float cl[20*128];
  __shared__ float cn2[20];
  int t = threadIdx.x, r0 = blockIdx.x*64;    // grid 16
  int row = t & 63, jg = t >> 6;
  float acc[5] = {0,0,0,0,0};
  float tpn = 0.f;
  if (t < 20) cn2[t] = 0.f;
  for (int ec=0; ec<384; ec+=128){
    __syncthreads();
    for (int i=t; i<64*128; i+=256){ int r=i/128, e=i-r*128; tp[r*129+e] = thetap[(long long)(r0+r)*384 + ec + e]; }
    for (int i=t; i<20*128; i+=256){ int r=i/128, e=i-r*128; cl[r*128+e] = cluster[r*384 + ec + e]; }
    __syncthreads();
    if (t < 20){ float s=0.f; for (int e=0;e<128;e++){ float v=cl[t*128+e]; s+=v*v; } cn2[t]+=s; }
    for (int e=0;e<128;e++){
      float tv = tp[row*129+e]; tpn += tv*tv;
      #pragma unroll
      for (int jj=0;jj<5;jj++) acc[jj] += cl[(jg*5+jj)*128+e]*tv;
    }
  }
  __syncthreads();
  #pragma unroll
  for (int jj=0;jj<5;jj++){
    int jc = jg*5+jj;
    float d = tpn + cn2[jc] - 2.f*acc[jj];
    m2 [(r0+row)*20 + jc] = d;
    km2[(r0+row)*20 + jc] = expf(-20.f*d);
  }
}

// ---------------- topic_p projection ----------------
__global__ void k_topicp(const float* __restrict__ topic, const float* __restrict__ tpw,
                         const float* __restrict__ tpb, float* __restrict__ topicp){
  int gid = blockIdx.x*256 + threadIdx.x;     // grid 150 -> 38400 exact
  int r = gid/384, c = gid%384;
  float s = 0.f;
  for (int k=0;k<200;k++) s += topic[r*200+k]*tpw[k*384+c];
  topicp[gid] = s + tpb[c];
}

// ---------------- TCR distances: M3, Km3 ----------------
__global__ void k_km3(const float* __restrict__ topicp, const float* __restrict__ cluster,
                      float* __restrict__ m3, float* __restrict__ km3){
  int gid = blockIdx.x*256 + threadIdx.x;     // grid 8, guard 2000
  if (gid >= 2000) return;
  int r = gid/20, jc = gid%20;
  float sa=0.f, sb=0.f, sab=0.f;
  for (int e=0;e<384;e++){
    float a = topicp[r*384+e], b = cluster[jc*384+e];
    sa += a*a; sb += b*b; sab += a*b;
  }
  float d = sa + sb - 2.f*sab;
  m3[gid] = d; km3[gid] = expf(-20.f*d);
}

// ---------------- NCE: cosine GEMM + per-(row,jblock) LSE partials ----------------
__global__ __launch_bounds__(256) void k_nce(const float* __restrict__ pbow,
                                             const float* __restrict__ bert,
                                             const float* __restrict__ pbnorm,
                                             const float* __restrict__ bertnorm,
                                             float* __restrict__ ncep, float* __restrict__ nced){
  __shared__ __align__(16) float pb[64*32];   // [e][32 rows]
  __shared__ __align__(16) float bt[64*128];  // [e][128 cols]
  __shared__ float pn[32], bn[128];
  int t = threadIdx.x;
  int rb = blockIdx.x & 31, jb = blockIdx.x >> 5;
  int r0 = rb*32, j0 = jb*128;
  int rg = t>>5, jg = t&31;
  float acc[4][4];
  #pragma unroll
  for (int i=0;i<4;i++){ acc[i][0]=0;acc[i][1]=0;acc[i][2]=0;acc[i][3]=0; }
  if (t < 32)  pn[t] = pbnorm[r0+t];
  if (t < 128) bn[t] = bertnorm[j0+t];
  for (int ec=0; ec<384; ec+=64){
    __syncthreads();
    for (int i=t; i<32*64; i+=256){ int r=i/64, e=i-r*64; pb[e*32+r] = pbow[(long long)(r0+r)*384 + ec + e]; }
    for (int i=t; i<128*64; i+=256){ int r=i/64, e=i-r*64; bt[e*128+r] = bert[(long long)(j0+r)*384 + ec + e]; }
    __syncthreads();
    for (int e=0;e<64;e++){
      float4 a4 = *(const float4*)&pb[e*32 + rg*4];
      float4 b4 = *(const float4*)&bt[e*128 + jg*4];
      float av[4] = {a4.x,a4.y,a4.z,a4.w};
      float bv[4] = {b4.x,b4.y,b4.z,b4.w};
      #pragma unroll
      for (int ii=0;ii<4;ii++)
        #pragma unroll
        for (int jj=0;jj<4;jj++) acc[ii][jj] += av[ii]*bv[jj];
    }
  }
  #pragma unroll
  for (int ii=0;ii<4;ii++){
    int grow = r0 + rg*4 + ii;
    float pnv = pn[rg*4+ii];
    float cv[4];
    #pragma unroll
    for (int jj=0;jj<4;jj++){
      cv[jj] = acc[ii][jj] / (pnv * bn[jg*4+jj]);
      int gcol = j0 + jg*4 + jj;
      if (gcol == grow) nced[grow] = cv[jj];
    }
    float m = fmaxf(fmaxf(cv[0],cv[1]), fmaxf(cv[2],cv[3]));
    float s = expf(cv[0]-m)+expf(cv[1]-m)+expf(cv[2]-m)+expf(cv[3]-m);
    for (int d=16; d>=1; d>>=1){
      float mo = __shfl_xor(m,d), so = __shfl_xor(s,d);
      lse_merge(m, s, mo, so);
    }
    if (jg == 0){ ncep[grow*16 + jb*2] = m; ncep[grow*16 + jb*2 + 1] = s; }
  }
}

// ---------------- NCE combine: full-row LSE, accumulate loss ----------------
__global__ void k_ncecomb(const float* __restrict__ ncep, const float* __restrict__ nced,
                          float* __restrict__ accs){
  int r = blockIdx.x*256 + threadIdx.x;       // grid 4 -> 1024 exact
  float M = -INFINITY, S = 0.f;
  for (int p=0;p<8;p++){
    float m = ncep[r*16 + p*2], s = ncep[r*16 + p*2 + 1];
    lse_merge(M, S, m, s);
  }
  float lse = M + logf(S);
  gAdd(accs+5, lse - nced[r]);
}

// ---------------- recon GEMM: X = theta @ beta ----------------
__global__ __launch_bounds__(256) void k_recon(const float* __restrict__ theta,
                                               const float* __restrict__ beta,
                                               float* __restrict__ X){
  __shared__ __align__(16) float th[50*128];  // [k][128 rows]
  __shared__ __align__(16) float bt[50*128];  // [k][128 cols]
  int t = threadIdx.x;
  int c0 = blockIdx.x*128, m0 = blockIdx.y*128;   // grid (391, 8)
  int rg = t>>4, cg = t&15;
  float acc[8][8];
  #pragma unroll
  for (int i=0;i<8;i++)
    #pragma unroll
    for (int j=0;j<8;j++) acc[i][j]=0.f;
  for (int kc=0; kc<100; kc+=50){
    __syncthreads();
    for (int i=t; i<128*50; i+=256){ int r=i/50, k=i-r*50; th[k*128+r] = theta[(m0+r)*100 + kc + k]; }
    for (int i=t; i<50*128; i+=256){ int k=i/128, cc=i-k*128; int col=c0+cc;
      bt[k*128+cc] = (col < 50000) ? beta[(long long)(kc+k)*50000 + col] : 0.f; }
    __syncthreads();
    for (int k=0;k<50;k++){
      float4 a0 = *(const float4*)&th[k*128 + rg*8];
      float4 a1 = *(const float4*)&th[k*128 + rg*8 + 4];
      float4 b0 = *(const float4*)&bt[k*128 + cg*8];
      float4 b1 = *(const float4*)&bt[k*128 + cg*8 + 4];
      float av[8] = {a0.x,a0.y,a0.z,a0.w,a1.x,a1.y,a1.z,a1.w};
      float bv[8] = {b0.x,b0.y,b0.z,b0.w,b1.x,b1.y,b1.z,b1.w};
      #pragma unroll
      for (int ii=0;ii<8;ii++)
        #pragma unroll
        for (int jj=0;jj<8;jj++) acc[ii][jj] += av[ii]*bv[jj];
    }
  }
  int col = c0 + cg*8;
  if (col < 50000){
    #pragma unroll
    for (int ii=0;ii<8;ii++){
      long long base = (long long)(m0 + rg*8 + ii)*50000 + col;
      float4 s0 = {acc[ii][0],acc[ii][1],acc[ii][2],acc[ii][3]};
      float4 s1 = {acc[ii][4],acc[ii][5],acc[ii][6],acc[ii][7]};
      *(float4*)(X + base) = s0;
      *(float4*)(X + base + 4) = s1;
    }
  }
}

// ---------------- per-column stats of X (dec BN) ----------------
__global__ void k_colstats(const float* __restrict__ X, float* __restrict__ xmean,
                           float* __restrict__ xrstd){
  __shared__ float ss[4][64], sq[4][64];
  int t = threadIdx.x, lane = t&63, rg = t>>6;
  int c = blockIdx.x*64 + lane;               // grid 782
  float s=0.f, q=0.f;
  if (c < 50000) for (int i=0;i<256;i++){ float v = X[(long long)(rg*256+i)*50000 + c]; s+=v; q+=v*v; }
  ss[rg][lane]=s; sq[rg][lane]=q;
  __syncthreads();
  if (rg==0 && c < 50000){
    s = ss[0][lane]+ss[1][lane]+ss[2][lane]+ss[3][lane];
    q = sq[0][lane]+sq[1][lane]+sq[2][lane]+sq[3][lane];
    float mean = s*(1.f/1024.f);
    float var  = q*(1.f/1024.f) - mean*mean;
    xmean[c] = mean; xrstd[c] = rsqrtf(var + 1e-5f);
  }
}

// ---------------- pass B: BN + online log-softmax + data dot per row ----------------
__global__ void k_passB(const float* __restrict__ X, const float* __restrict__ data,
                        const float* __restrict__ xmean, const float* __restrict__ xrstd,
                        const float* __restrict__ dbn, float* __restrict__ accs){
  __shared__ float rm[4], rs[4], ra[4], rb[4];
  int t = threadIdx.x, w = t>>6, l = t&63;
  int r = blockIdx.x;                         // grid 1024
  float m = -INFINITY, sE = 0.f, sdy = 0.f, sd = 0.f;
  for (int base = t*4; base < 50000; base += 1024){
    float4 x4 = *(const float4*)(X + (long long)r*50000 + base);
    float4 d4 = *(const float4*)(data + (long long)r*50000 + base);
    float4 mn = *(const float4*)(xmean + base);
    float4 rs4= *(const float4*)(xrstd + base);
    float4 bb = *(const float4*)(dbn + base);
    float xs[4] = {x4.x,x4.y,x4.z,x4.w};
    float ds[4] = {d4.x,d4.y,d4.z,d4.w};
    float ms[4] = {mn.x,mn.y,mn.z,mn.w};
    float rr[4] = {rs4.x,rs4.y,rs4.z,rs4.w};
    float bs[4] = {bb.x,bb.y,bb.z,bb.w};
    #pragma unroll
    for (int q=0;q<4;q++){
      float y = (xs[q]-ms[q])*rr[q] + bs[q];
      float Mn = fmaxf(m, y);
      sE = sE*expf(m-Mn) + expf(y-Mn);
      m = Mn;
      sdy += ds[q]*y; sd += ds[q];
    }
  }
  for (int d=1; d<64; d<<=1){
    float mo=__shfl_xor(m,d), so=__shfl_xor(sE,d);
    lse_merge(m, sE, mo, so);
  }
  sdy = wsum(sdy); sd = wsum(sd);
  if (l==0){ rm[w]=m; rs[w]=sE; ra[w]=sdy; rb[w]=sd; }
  __syncthreads();
  if (t==0){
    float M=rm[0], S=rs[0];
    for (int q=1;q<4;q++) lse_merge(M, S, rm[q], rs[q]);
    float lse = M + logf(S);
    float sdyT = ra[0]+ra[1]+ra[2]+ra[3];
    float sdT  = rb[0]+rb[1]+rb[2]+rb[3];
    gAdd(accs+0, sdyT - lse*sdT);
  }
}

// ---------------- cooperative Sinkhorn: ECR (196 blocks, LDS-resident Km) + DCR + TCR ----------------
// dynamic LDS: 25700 floats (102.8KB). ECR: Km slice [100][256] at stride 257 (2-way bank alias = free).
__global__ __launch_bounds__(256) void k_sinkhorn(const float* __restrict__ km,
                                                  const float* __restrict__ km2,
                                                  const float* __restrict__ m2,
                                                  const float* __restrict__ km3,
                                                  const float* __restrict__ m3,
                                                  const float* __restrict__ clmass,
                                                  const float* __restrict__ docw,
                                                  const float* __restrict__ topw,
                                                  float* __restrict__ tbuf,
                                                  float* __restrict__ accs){
  extern __shared__ float dynsm[];
  __shared__ float u_lds[100];
  __shared__ float vcol[256];
  __shared__ float twv[4*128];
  __shared__ float redl[8];
  __shared__ float slds[20], vl2[20];
  cg::grid_group grid = cg::this_grid();
  const float EPS = 1e-16f;
  int t = threadIdx.x, bid = blockIdx.x, w = t>>6, l = t&63;

  if (bid < 196){                              // ===== ECR =====
    float* kml = dynsm;                        // [100][257]
    int j0 = bid*256;
    // stage Km slice: thread t owns column jl=t across all k (coalesced global, 2-way LDS)
    {
      int j = j0 + t;
      for (int k=0; k<100; k++)
        kml[k*257 + t] = (j < 50000) ? km[(long long)k*50000 + j] : 0.f;
    }
    bool act = (j0 + t) < 50000;
    if (t < 100) u_lds[t] = 0.01f;
    __syncthreads();
    for (int n=0; n<100; n++){
      float v = 0.f;
      if (act){
        float s0=0,s1=0,s2=0,s3=0;
        #pragma unroll 25
        for (int k=0;k<100;k+=4){
          s0 += kml[(k  )*257 + t]*u_lds[k  ];
          s1 += kml[(k+1)*257 + t]*u_lds[k+1];
          s2 += kml[(k+2)*257 + t]*u_lds[k+2];
          s3 += kml[(k+3)*257 + t]*u_lds[k+3];
        }
        v = (1.f/50000.f)/(((s0+s1)+(s2+s3)) + EPS);
      }
      vcol[t] = v;
      __syncthreads();
      float t1=0.f, t2=0.f;
      for (int c=0;c<64;c++){
        float vv = vcol[w*64+c];               // broadcast
        t1 += kml[l*257 + w*64+c]*vv;          // 2-way bank alias: free
        if (l < 36) t2 += kml[(64+l)*257 + w*64+c]*vv;
      }
      twv[w*128 + l] = t1;
      twv[w*128 + 64 + l] = (l < 36) ? t2 : 0.f;
      __syncthreads();
      if (t < 100){
        float bt_ = twv[t] + twv[128+t] + twv[256+t] + twv[384+t];
        gAdd(&tbuf[n*128 + t], bt_);
      }
      grid.sync();
      if (t < 100) u_lds[t] = 0.01f/(tbuf[n*128+t] + EPS);
      __syncthreads();
    }
    // final loss: vcol holds v_100, u_lds holds u_100
    float lsum = 0.f;
    if (act){
      float v = vcol[t];
      float s2 = 0.f;
      for (int k=0;k<100;k++){
        float kv = kml[k*257 + t];
        if (kv > 0.f){                         // Km underflow -> ref contribution is exactly 0 (avoid 0*inf)
          float mm = -0.05f*logf(kv);          // recover dist from Km
          s2 += u_lds[k]*kv*mm;
        }
      }
      lsum = s2*v;
    }
    lsum = wsum(lsum);
    if (l==0) redl[w] = lsum;
    __syncthreads();
    if (t==0) gAdd(accs+2, redl[0]+redl[1]+redl[2]+redl[3]);
  }
  else if (bid == 196){                        // ===== DCR (1024x20) =====
    float* km2l = dynsm;                       // [1024][20] staged
    for (int i=t; i<20480; i+=256) km2l[i] = km2[i];
    int r = t*4;
    float a0=docw[r], a1=docw[r+1], a2=docw[r+2], a3=docw[r+3];
    float u0=1.f/1024.f, u1=u0, u2=u0, u3=u0;
    if (t < 20){ slds[t]=0.f; }
    __syncthreads();
    for (int n=0;n<100;n++){
      for (int jo=0;jo<20;jo++){
        int jx = (jo + t) % 20;
        float p = km2l[(r  )*20+jx]*u0 + km2l[(r+1)*20+jx]*u1
                + km2l[(r+2)*20+jx]*u2 + km2l[(r+3)*20+jx]*u3;
        atomicAdd(&slds[jx], p);
      }
      __syncthreads();
      if (t < 20){ vl2[t] = clmass[t]/(slds[t]+EPS); slds[t]=0.f; }
      __syncthreads();
      float s0=0,s1=0,s2=0,s3=0;
      for (int jx=0;jx<20;jx++){
        float vv = vl2[jx];
        s0 += km2l[(r  )*20+jx]*vv; s1 += km2l[(r+1)*20+jx]*vv;
        s2 += km2l[(r+2)*20+jx]*vv; s3 += km2l[(r+3)*20+jx]*vv;
      }
      u0 = a0/(s0+EPS); u1 = a1/(s1+EPS); u2 = a2/(s2+EPS); u3 = a3/(s3+EPS);
      grid.sync();
    }
    float ls = 0.f;
    for (int jx=0;jx<20;jx++){
      float vv = vl2[jx];
      ls += u0*km2l[(r  )*20+jx]*vv*m2[(r  )*20+jx];
      ls += u1*km2l[(r+1)*20+jx]*vv*m2[(r+1)*20+jx];
      ls += u2*km2l[(r+2)*20+jx]*vv*m2[(r+2)*20+jx];
      ls += u3*km2l[(r+3)*20+jx]*vv*m2[(r+3)*20+jx];
    }
    ls = wsum(ls);
    if (l==0) redl[w] = ls;
    __syncthreads();
    if (t==0) gAdd(accs+3, redl[0]+redl[1]+redl[2]+redl[3]);
  }
  else {                                       // ===== TCR (100x20) =====
    float* km3l = dynsm;                       // [100][20] staged
    for (int i=t; i<2000; i+=256) km3l[i] = km3[i];
    bool act = t < 100; int r = t;
    float a = act ? topw[r] : 0.f;
    float uu = 0.01f;
    if (t < 20) slds[t]=0.f;
    __syncthreads();
    for (int n=0;n<100;n++){
      if (act){
        for (int jo=0;jo<20;jo++){
          int jx = (jo + t) % 20;
          atomicAdd(&slds[jx], km3l[r*20+jx]*uu);
        }
      }
      __syncthreads();
      if (t < 20){ vl2[t] = clmass[t]/(slds[t]+EPS); slds[t]=0.f; }
      __syncthreads();
      if (act){
        float s = 0.f;
        for (int jx=0;jx<20;jx++) s += km3l[r*20+jx]*vl2[jx];
        uu = a/(s+EPS);
      }
      grid.sync();
    }
    float ls = 0.f;
    if (act) for (int jx=0;jx<20;jx++) ls += uu*km3l[r*20+jx]*vl2[jx]*m3[r*20+jx];
    ls = wsum(ls);
    if (l==0) redl[w] = ls;
    __syncthreads();
    if (t==0) gAdd(accs+4, redl[0]+redl[1]+redl[2]+redl[3]);
  }
}

// ---------------- finalize 6 outputs ----------------
__global__ void k_final(const float* __restrict__ accs, const int* __restrict__ epoch,
                        float* __restrict__ out){
  if (threadIdx.x==0 && blockIdx.x==0){
    float recon = -accs[0]*(1.f/1024.f);
    float kl    =  accs[1]*(1.f/1024.f);
    float tm    = recon + kl;
    float ecr   = 250.f*accs[2];
    float dcr   = 250.f*accs[3];
    float tcr   = (epoch[0] > 10) ? 250.f*accs[4] : 0.f;
    float nce   = 10.f*accs[5]*(1.f/1024.f);
    out[0] = tm + ecr + dcr + tcr + nce;
    out[1] = tm; out[2] = ecr; out[3] = dcr; out[4] = tcr; out[5] = nce;
  }
}

// ---------------- launch ----------------
extern "C" void kernel_launch(void* const* d_in, const int* in_sizes, int n_in,
                              void* d_out, int out_size, void* d_ws, size_t ws_size,
                              hipStream_t stream){
  (void)in_sizes; (void)n_in; (void)out_size; (void)ws_size; // needs ws >= ~252MB
  const float* data   = (const float*)d_in[0];
  const float* bert   = (const float*)d_in[1];
  const float* eps    = (const float*)d_in[2];
  const float* fc11w  = (const float*)d_in[3];
  const float* fc11b  = (const float*)d_in[4];
  const float* fc12w  = (const float*)d_in[5];
  const float* fc12b  = (const float*)d_in[6];
  const float* fc21w  = (const float*)d_in[7];
  const float* fc21b  = (const float*)d_in[8];
  const float* fc22w  = (const float*)d_in[9];
  const float* fc22b  = (const float*)d_in[10];
  const float* mbb    = (const float*)d_in[11];
  const float* lbb    = (const float*)d_in[12];
  const float* dbn    = (const float*)d_in[13];
  const float* word   = (const float*)d_in[14];
  const float* topic  = (const float*)d_in[15];
  const float* thw    = (const float*)d_in[16];
  const float* thb    = (const float*)d_in[17];
  const float* tpw    = (const float*)d_in[18];
  const float* tpb    = (const float*)d_in[19];
  const float* prw    = (const float*)d_in[20];
  const float* prb    = (const float*)d_in[21];
  const float* clust  = (const float*)d_in[22];
  const float* clm    = (const float*)d_in[23];
  const float* docw   = (const float*)d_in[24];
  const float* topwts = (const float*)d_in[25];
  const int*   epoch  = (const int*)d_in[26];

  float* ws = (float*)d_ws;
  float* X      = ws + OFF_X;
  float* BETA   = ws + OFF_BETA;
  float* KM     = ws + OFF_KM;
  float* E1     = ws + OFF_E1;
  float* E2     = ws + OFF_E2;
  float* MUPRE  = ws + OFF_MUPRE;
  float* LVPRE  = ws + OFF_LVPRE;
  float* BNM    = ws + OFF_BNM;
  float* BNR    = ws + OFF_BNR;
  float* THETA  = ws + OFF_THETA;
  float* THETAP = ws + OFF_THETAP;
  float* PBOW   = ws + OFF_PBOW;
  float* PBN    = ws + OFF_PBN;
  float* BERTN  = ws + OFF_BERTN;
  float* KM2    = ws + OFF_KM2;
  float* M2     = ws + OFF_M2;
  float* TOPICP = ws + OFF_TOPICP;
  float* KM3    = ws + OFF_KM3;
  float* M3     = ws + OFF_M3;
  float* XMEAN  = ws + OFF_XMEAN;
  float* XRSTD  = ws + OFF_XRSTD;
  float* TBUF   = ws + OFF_TBUF;
  float* NCEP   = ws + OFF_NCEP;
  float* NCED   = ws + OFF_NCED;
  float* ACC    = ws + OFF_ACC;

  // allow 102.8KB dynamic LDS for the sinkhorn kernel (idempotent, host-side, graph-safe)
  static int sh_attr_set = 0;
  if (!sh_attr_set){
    hipFuncSetAttribute((const void*)k_sinkhorn,
                        hipFuncAttributeMaxDynamicSharedMemorySize, 25700*4);
    sh_attr_set = 1;
  }

  k_zero<<<13, 256, 0, stream>>>(TBUF, ACC);
  k_gemm1<<<dim3(16,25), 256, 0, stream>>>(data, fc11w, X);         // partials live at front of X
  k_e1red<<<800, 256, 0, stream>>>(X, fc11b, E1);
  k_e2<<<64, 256, 0, stream>>>(E1, fc12w, fc12b, E2);
  k_mulv<<<64, 256, 0, stream>>>(E2, fc21w, fc21b, fc22w, fc22b, MUPRE, LVPRE);
  k_bnstats<<<4, 256, 0, stream>>>(MUPRE, LVPRE, BNM, BNR);
  k_theta<<<256, 256, 0, stream>>>(MUPRE, LVPRE, BNM, BNR, mbb, lbb, eps, THETA, ACC);
  k_topicword<<<196, 256, 0, stream>>>(topic, word, BETA, KM);
  k_proj<<<3072, 256, 0, stream>>>(THETA, thw, thb, prw, prb, THETAP, PBOW);
  k_norms<<<512, 256, 0, stream>>>(PBOW, bert, PBN, BERTN);
  k_km2<<<16, 256, 0, stream>>>(THETAP, clust, M2, KM2);
  k_topicp<<<150, 256, 0, stream>>>(topic, tpw, tpb, TOPICP);
  k_km3<<<8, 256, 0, stream>>>(TOPICP, clust, M3, KM3);
  k_nce<<<256, 256, 0, stream>>>(PBOW, bert, PBN, BERTN, NCEP, NCED);
  k_ncecomb<<<4, 256, 0, stream>>>(NCEP, NCED, ACC);
  k_recon<<<dim3(391,8), 256, 0, stream>>>(THETA, BETA, X);
  k_colstats<<<782, 256, 0, stream>>>(X, XMEAN, XRSTD);
  k_passB<<<1024, 256, 0, stream>>>(X, data, XMEAN, XRSTD, dbn, ACC);

  {
    const float* a_km  = KM;
    const float* a_km2 = KM2; const float* a_m2  = M2;
    const float* a_km3 = KM3; const float* a_m3  = M3;
    const float* a_clm = clm; const float* a_dw  = docw; const float* a_tw = topwts;
    float* a_tb = TBUF; float* a_ac = ACC;
    void* cargs[] = { (void*)&a_km, (void*)&a_km2, (void*)&a_m2,
                      (void*)&a_km3, (void*)&a_m3, (void*)&a_clm, (void*)&a_dw,
                      (void*)&a_tw, (void*)&a_tb, (void*)&a_ac };
    hipLaunchCooperativeKernel((void*)k_sinkhorn, dim3(198), dim3(256), cargs,
                               25700*4, stream);
  }

  k_final<<<1, 64, 0, stream>>>(ACC, epoch, (float*)d_out);
}